// Round 3
// baseline (172.774 us; speedup 1.0000x reference)
//
#include <hip/hip_runtime.h>
#include <hip/hip_bf16.h>
#include <math.h>

#define B_   128
#define LQ_  64
#define LD_  512
#define E_   300
#define K_   11
#define NCH  8      // d-chunks of 64 rows
#define DCH  64
#define NG   4      // 16-row d-groups per chunk (double-buffered LDS staging)
#define NT   10     // e-tiles of 32 (300 padded to 320)
#define GF   (16 * E_)   // floats per 16-row group = 4800 (19200 B, contiguous)

typedef __bf16  bf16x8  __attribute__((ext_vector_type(8)));
typedef float   floatx4 __attribute__((ext_vector_type(4)));

// factorized RBF: kernel k (1..10, mu=0.9..-0.9 step -0.2, sigma=0.1):
//   exp(-50(s-mu_k)^2) = t_k * CK2[k],  t_1 = exp(90s-50s^2), t_{k+1} = t_k*exp(-20s)
__device__ __constant__ float CK2_C[10] =
    {2.576757e-18f, 2.288464e-11f, 3.726653e-06f, 1.110900e-02f, 6.065307e-01f,
     6.065307e-01f, 1.110900e-02f, 3.726653e-06f, 2.288464e-11f, 2.576757e-18f};

__device__ __forceinline__ unsigned int pk2(float x, float y) {
    __hip_bfloat162 h = __float22bfloat162_rn(make_float2(x, y));
    union { __hip_bfloat162 h2; unsigned int u; } c;
    c.h2 = h;
    return c.u;
}

// async global->LDS, 16 B per lane; LDS dest = uniform base + lane*16 (HW rule)
__device__ __forceinline__ void gload16(const float* g, float* l) {
    __builtin_amdgcn_global_load_lds(
        (const __attribute__((address_space(1))) unsigned int*)g,
        (__attribute__((address_space(3))) unsigned int*)l, 16, 0, 0);
}

// Block = (batch, 64-row d-chunk), 256 thr = 4 waves; wave w owns q-rows w*16..+16.
// Q lives in REGISTERS (40 VGPRs of A-fragments per lane) instead of LDS: LDS is
// only the 38.4-KB D double-buffer -> 4 blocks/CU, 16 waves/CU, ALL 1024 blocks
// resident in one round. That TLP is what covers the per-group vmcnt/barrier
// stalls that held round-2 at 770 GB/s / 20% occupancy / 20% VALUBusy.
// D staging: 16-row groups (19.2 KB CONTIGUOUS) via global_load_lds (1024-B
// wave requests), double-buffered, counted vmcnt(5) so next group's loads stay
// in flight across raw s_barriers. Epilogue pools directly in MFMA C-layout
// (shfl over l15) -> no LDS transpose, 2 fewer barriers.
__global__ __launch_bounds__(256, 4) void knrm_main(
    const float* __restrict__ Q, const float* __restrict__ D,
    const float* __restrict__ mask_d, float* __restrict__ psum)
{
    const int b = blockIdx.x, ch = blockIdx.y, d0 = ch * DCH;
    const int tid  = threadIdx.x;
    const int lane = tid & 63;
    const int w    = tid >> 6;      // 0..3, wave's q-slice
    const int quad = lane >> 4;
    const int l15  = lane & 15;

    __shared__ __align__(16) float dbuf[2 * GF];   // 38400 B, 2 x 16 rows fp32
    __shared__ __align__(16) float md_s[DCH];

    const float* gD = D + ((size_t)b * LD_ + d0) * E_;  // block's 64 rows, contiguous

    // stage 16-row group g into dbuf[(g&1)]: wave w copies floats w*1200..+1200
    // (4800 B contiguous) = 4 full 1024-B instrs + one 704-B (44-lane) tail.
#define STAGE(g) do {                                                     \
        const float* sB = gD + (g) * GF + w * 1200;                       \
        float*       dB = &dbuf[((g) & 1) * GF + w * 1200];               \
        gload16(sB +       lane * 4, dB);                                 \
        gload16(sB + 256 + lane * 4, dB + 256);                           \
        gload16(sB + 512 + lane * 4, dB + 512);                           \
        gload16(sB + 768 + lane * 4, dB + 768);                           \
        if (lane < 44) gload16(sB + 1024 + lane * 4, dB + 1024);          \
    } while (0)

    STAGE(0);   // in flight under Q fragment loads + norm

    // ---- Q A-fragments -> registers (fp32 -> bf16), fused row norm ----
    // Lane (l15,quad) holds q-row w*16+l15, cols t*32+quad*8..+8 (10 tiles).
    const float tm0 = (quad <= 1) ? 1.f : 0.f;            // tile-9 validity
    const float tm1 = (quad == 0) ? 1.f : 0.f;            // (cols >= 300 masked)
    const float* qp = Q + ((size_t)b * LQ_ + w * 16 + l15) * E_;

    bf16x8 qf[NT];   // 40 VGPRs
    float ssq = 0.f;
#pragma unroll
    for (int t = 0; t < NT; ++t) {
        const int c0 = t * 32 + quad * 8;
        float4 a, c;
        if (t < NT - 1) {
            a = *(const float4*)(qp + c0);
            c = *(const float4*)(qp + c0 + 4);
        } else {   // tile 9: quad0 fully valid, quad1 half, quads 2-3 invalid
            a = *(const float4*)(qp + (quad <= 1 ? c0 : 0));
            c = *(const float4*)(qp + (quad == 0 ? c0 + 4 : 0));
            a.x *= tm0; a.y *= tm0; a.z *= tm0; a.w *= tm0;
            c.x *= tm1; c.y *= tm1; c.z *= tm1; c.w *= tm1;
        }
        ssq += a.x * a.x + a.y * a.y + a.z * a.z + a.w * a.w;
        ssq += c.x * c.x + c.y * c.y + c.z * c.z + c.w * c.w;
        union { uint4 u; bf16x8 v; } qc;
        qc.u = make_uint4(pk2(a.x, a.y), pk2(a.z, a.w),
                          pk2(c.x, c.y), pk2(c.z, c.w));
        qf[t] = qc.v;
    }
    // full-row ssq: 4 quads of same l15 covered disjoint col ranges
    ssq += __shfl_xor(ssq, 16);
    ssq += __shfl_xor(ssq, 32);
    const float qinv = 1.0f / fmaxf(sqrtf(ssq), 1e-12f);   // for q-row w*16+l15

    if (tid < DCH) md_s[tid] = mask_d[(size_t)b * LD_ + d0 + tid];
    __syncthreads();   // drains STAGE(0) (vmcnt 0) + md_s visible

    // ---- group loop: staged-LDS D fragments + MFMA ----
    // B-frag lane (l15,quad): group row l15 (LDS stride 300 words = 12 mod 32
    // -> 2-way banks, free), cols t*32+quad*8..+8.
    floatx4 acc[NG];
    float dinvv[NG];
    floatx4 zero4 = {0.f, 0.f, 0.f, 0.f};
#pragma unroll
    for (int g = 0; g < NG; ++g) acc[g] = zero4;

#pragma unroll
    for (int g = 0; g < NG; ++g) {
        if (g + 1 < NG) STAGE(g + 1);            // prefetch next group
        // wait for group g's stage (counted: keep g+1's 5 loads in flight)
        if (g == 1 || g == 2) asm volatile("s_waitcnt vmcnt(5)" ::: "memory");
        if (g == 3)           asm volatile("s_waitcnt vmcnt(0)" ::: "memory");
        if (g) {                                  // g=0 covered by __syncthreads
            __builtin_amdgcn_s_barrier();         // all waves' stage(g) landed
            asm volatile("" ::: "memory");
        }

        const float* rowp = &dbuf[(g & 1) * GF + l15 * E_];
        float lssd = 0.f;
#pragma unroll
        for (int t = 0; t < NT; ++t) {
            const int c0 = t * 32 + quad * 8;
            float4 a, c;
            if (t < NT - 1) {
                a = *(const float4*)(rowp + c0);
                c = *(const float4*)(rowp + c0 + 4);
            } else {   // tile 9 masking (rows are 300 floats in LDS)
                a = *(const float4*)(rowp + (quad <= 1 ? c0 : 0));
                c = *(const float4*)(rowp + (quad == 0 ? c0 + 4 : 0));
                a.x *= tm0; a.y *= tm0; a.z *= tm0; a.w *= tm0;
                c.x *= tm1; c.y *= tm1; c.z *= tm1; c.w *= tm1;
            }
            lssd += a.x * a.x + a.y * a.y + a.z * a.z + a.w * a.w;
            lssd += c.x * c.x + c.y * c.y + c.z * c.z + c.w * c.w;

            union { uint4 u; bf16x8 v; } bc;
            bc.u = make_uint4(pk2(a.x, a.y), pk2(a.z, a.w),
                              pk2(c.x, c.y), pk2(c.z, c.w));
            acc[g] = __builtin_amdgcn_mfma_f32_16x16x32_bf16(qf[t], bc.v, acc[g], 0, 0, 0);
        }
        // d inv-norm for group rows: 4 quads covered disjoint col ranges
        lssd += __shfl_xor(lssd, 16);
        lssd += __shfl_xor(lssd, 32);
        dinvv[g] = 1.0f / fmaxf(sqrtf(lssd), 1e-12f);

        if (g < 2) {   // before STAGE(g+2) may overwrite dbuf[g&1]
            asm volatile("" ::: "memory");
            __builtin_amdgcn_s_barrier();
            asm volatile("" ::: "memory");
        }
    }

    // ---- epilogue: RBF pooling directly in MFMA C-layout ----
    // Lane holds acc[g][r] = sim(q = w*16+quad*4+r, d = g*16+l15) (unnormalized).
    float qr[4], mdv[4];
#pragma unroll
    for (int r = 0; r < 4; ++r) qr[r] = __shfl(qinv, quad * 4 + r);  // qinv of row quad*4+r
#pragma unroll
    for (int g = 0; g < NG; ++g) mdv[g] = md_s[g * 16 + l15];

    float kacc[4][K_];
#pragma unroll
    for (int r = 0; r < 4; ++r)
#pragma unroll
        for (int k = 0; k < K_; ++k) kacc[r][k] = 0.f;

#pragma unroll
    for (int g = 0; g < NG; ++g) {
#pragma unroll
        for (int r = 0; r < 4; ++r) {
            const float s = acc[g][r] * qr[r] * dinvv[g];
            const float m = mdv[g];
            // kernel 0 (sigma=0.001): exact
            const float df0 = s - 1.0f;
            kacc[r][0] = fmaf(__expf(df0 * df0 * -500000.0f), m, kacc[r][0]);
            // kernels 1..10: factorized (3 exps per sim)
            const float t1 = __expf(fmaf(-50.0f * s, s, 90.0f * s));  // arg <= 40.5
            const float rr = __expf(-20.0f * s);
            float tt = t1 * m;
#pragma unroll
            for (int k = 1; k < K_; ++k) {
                kacc[r][k] = fmaf(tt, CK2_C[k - 1], kacc[r][k]);
                tt *= rr;
            }
        }
    }
    // sum over the 16 d-columns (l15 lanes within each quad group)
#pragma unroll
    for (int msk = 1; msk <= 8; msk <<= 1)
#pragma unroll
        for (int r = 0; r < 4; ++r)
#pragma unroll
            for (int k = 0; k < K_; ++k)
                kacc[r][k] += __shfl_xor(kacc[r][k], msk);

    if (l15 == 0) {
#pragma unroll
        for (int r = 0; r < 4; ++r) {
            const int q = w * 16 + quad * 4 + r;
            const size_t base = (((size_t)b * LQ_ + q) * NCH + ch) * K_;
#pragma unroll
            for (int k = 0; k < K_; ++k) psum[base + k] = kacc[r][k];
        }
    }
#undef STAGE
}

// Combine chunk partials, log-pool, dense + tanh. One wave per batch.
__global__ __launch_bounds__(64) void knrm_final(
    const float* __restrict__ psum, const float* __restrict__ mask_q,
    const float* __restrict__ dw, const float* __restrict__ db,
    float* __restrict__ out)
{
    const int b = blockIdx.x;
    const int q = threadIdx.x;  // 0..63

    const float* pp = psum + ((size_t)b * LQ_ + q) * (NCH * K_);
    union { float4 v[NCH * K_ / 4]; float f[NCH * K_]; } buf;  // 88 floats
#pragma unroll
    for (int i = 0; i < NCH * K_ / 4; ++i)
        buf.v[i] = *(const float4*)(pp + i * 4);

    float t = 0.0f;
#pragma unroll
    for (int k = 0; k < K_; ++k) {
        float p = 0.0f;
#pragma unroll
        for (int c = 0; c < NCH; ++c) p += buf.f[c * K_ + k];
        p = fmaxf(p, 1e-10f);
        t += logf(p) * dw[k];
    }
    t *= 0.01f * mask_q[(size_t)b * LQ_ + q];

#pragma unroll
    for (int m = 32; m >= 1; m >>= 1) t += __shfl_xor(t, m);
    if (q == 0) out[b] = tanhf(t + db[0]);
}

extern "C" void kernel_launch(void* const* d_in, const int* in_sizes, int n_in,
                              void* d_out, int out_size, void* d_ws, size_t ws_size,
                              hipStream_t stream) {
    const float* Q   = (const float*)d_in[0];  // [B, LQ, E]
    const float* D   = (const float*)d_in[1];  // [B, LD, E]
    const float* mq  = (const float*)d_in[2];  // [B, LQ]
    const float* md  = (const float*)d_in[3];  // [B, LD]
    const float* dw  = (const float*)d_in[4];  // [1, K]
    const float* db  = (const float*)d_in[5];  // [1]
    float* out  = (float*)d_out;               // [B, 1]
    float* psum = (float*)d_ws;                // [B][LQ][8][K] = 2.9 MB

    dim3 grid(B_, NCH);   // linear id = b + 128*ch -> XCD = b%8: same-batch
    knrm_main<<<grid, 256, 0, stream>>>(Q, D, md, psum);   // chunks share L2 Q
    knrm_final<<<B_, 64, 0, stream>>>(psum, mq, dw, db, out);
}

// Round 5
// 140.388 us; speedup vs baseline: 1.2307x; 1.2307x over previous
//
#include <hip/hip_runtime.h>
#include <hip/hip_bf16.h>
#include <math.h>

#define B_   128
#define LQ_  64
#define LD_  512
#define E_   300
#define K_   11
#define NCH  8      // d-chunks of 64 rows
#define DCH  64
#define NG   4      // 16-row d-groups per chunk (double-buffered LDS staging)
#define NT   10     // e-tiles of 32 (300 padded to 320)
#define CSTR 68     // epilogue sims row stride (floats)
#define GF   (16 * E_)   // floats per 16-row group = 4800 (19200 B, contiguous)

typedef __bf16  bf16x8  __attribute__((ext_vector_type(8)));
typedef float   floatx4 __attribute__((ext_vector_type(4)));

// factorized RBF: kernel k (1..10, mu=0.9..-0.9 step -0.2, sigma=0.1):
//   exp(-50(s-mu_k)^2) = t_k * CK2[k],  t_1 = exp(90s-50s^2), t_{k+1} = t_k*exp(-20s)
__device__ __constant__ float CK2_C[10] =
    {2.576757e-18f, 2.288464e-11f, 3.726653e-06f, 1.110900e-02f, 6.065307e-01f,
     6.065307e-01f, 1.110900e-02f, 3.726653e-06f, 2.288464e-11f, 2.576757e-18f};

__device__ __forceinline__ unsigned int pk2(float x, float y) {
    __hip_bfloat162 h = __float22bfloat162_rn(make_float2(x, y));
    union { __hip_bfloat162 h2; unsigned int u; } c;
    c.h2 = h;
    return c.u;
}

// async global->LDS, 16 B per lane; LDS dest = uniform base + lane*16 (HW rule)
__device__ __forceinline__ void gload16(const float* g, float* l) {
    __builtin_amdgcn_global_load_lds(
        (const __attribute__((address_space(1))) unsigned int*)g,
        (__attribute__((address_space(3))) unsigned int*)l, 16, 0, 0);
}

// D double-buffer; dead after the group loop, so the epilogue sims alias it.
union __align__(16) ShD {
    float dbuf[2 * GF];     // 38400 B: 2 x 16 D-rows fp32
    float cs[LQ_ * CSTR];   // 17408 B: normalized sims (64q x 64d)
};

// Block = (batch, 64-row d-chunk), 256 thr = 4 waves; wave w owns q-rows w*16..+16.
// Q lives in REGISTERS (40 VGPRs of A-fragments/lane); LDS is only the 38.4-KB
// D double-buffer -> 4 blocks/CU, all 1024 blocks resident (round-3 showed this
// lifts HBM 770 -> 2400 GB/s). Round-3's regression was a register cliff: 44
// live kacc accumulators + heuristic 64-VGPR allocation => 125 MB/dispatch of
// scratch spill (WRITE_SIZE 3->69 MB). Fix: epilogue repartitions through LDS
// (aliasing dbuf) so only 11 kacc regs are live, and launch_bounds(256,2) (the
// round-2 config that allocated 88 regs, no spill) removes the artificial cap.
// D staging: 16-row groups (19.2 KB CONTIGUOUS) via global_load_lds (1024-B
// wave requests), double-buffered, counted vmcnt(5) so the next group's loads
// stay in flight across raw s_barriers.
__global__ __launch_bounds__(256, 2) void knrm_main(
    const float* __restrict__ Q, const float* __restrict__ D,
    const float* __restrict__ mask_d, float* __restrict__ psum)
{
    const int b = blockIdx.x, ch = blockIdx.y, d0 = ch * DCH;
    const int tid  = threadIdx.x;
    const int lane = tid & 63;
    const int w    = tid >> 6;      // 0..3, wave's q-slice
    const int quad = lane >> 4;
    const int l15  = lane & 15;

    __shared__ ShD sh;
    __shared__ __align__(16) float md_s[DCH];

    const float* gD = D + ((size_t)b * LD_ + d0) * E_;  // block's 64 rows, contiguous

    // stage 16-row group g into dbuf[(g&1)]: wave w copies floats w*1200..+1200
    // (4800 B contiguous) = 4 full 1024-B instrs + one 704-B (44-lane) tail.
#define STAGE(g) do {                                                     \
        const float* sB = gD + (g) * GF + w * 1200;                       \
        float*       dB = &sh.dbuf[((g) & 1) * GF + w * 1200];            \
        gload16(sB +       lane * 4, dB);                                 \
        gload16(sB + 256 + lane * 4, dB + 256);                           \
        gload16(sB + 512 + lane * 4, dB + 512);                           \
        gload16(sB + 768 + lane * 4, dB + 768);                           \
        if (lane < 44) gload16(sB + 1024 + lane * 4, dB + 1024);          \
    } while (0)

    STAGE(0);   // in flight under Q fragment loads + norm

    // ---- Q A-fragments -> registers (fp32 -> bf16), fused row norm ----
    // Lane (l15,quad) holds q-row w*16+l15, cols t*32+quad*8..+8 (10 tiles).
    const float tm0 = (quad <= 1) ? 1.f : 0.f;            // tile-9 validity
    const float tm1 = (quad == 0) ? 1.f : 0.f;            // (cols >= 300 masked)
    const float* qp = Q + ((size_t)b * LQ_ + w * 16 + l15) * E_;

    bf16x8 qf[NT];   // 40 VGPRs
    float ssq = 0.f;
#pragma unroll
    for (int t = 0; t < NT; ++t) {
        const int c0 = t * 32 + quad * 8;
        float4 a, c;
        if (t < NT - 1) {
            a = *(const float4*)(qp + c0);
            c = *(const float4*)(qp + c0 + 4);
        } else {   // tile 9: quad0 fully valid, quad1 half, quads 2-3 invalid
            a = *(const float4*)(qp + (quad <= 1 ? c0 : 0));
            c = *(const float4*)(qp + (quad == 0 ? c0 + 4 : 0));
            a.x *= tm0; a.y *= tm0; a.z *= tm0; a.w *= tm0;
            c.x *= tm1; c.y *= tm1; c.z *= tm1; c.w *= tm1;
        }
        ssq += a.x * a.x + a.y * a.y + a.z * a.z + a.w * a.w;
        ssq += c.x * c.x + c.y * c.y + c.z * c.z + c.w * c.w;
        union { uint4 u; bf16x8 v; } qc;
        qc.u = make_uint4(pk2(a.x, a.y), pk2(a.z, a.w),
                          pk2(c.x, c.y), pk2(c.z, c.w));
        qf[t] = qc.v;
    }
    // full-row ssq: 4 quads of same l15 covered disjoint col ranges
    ssq += __shfl_xor(ssq, 16);
    ssq += __shfl_xor(ssq, 32);
    const float qinv = 1.0f / fmaxf(sqrtf(ssq), 1e-12f);   // for q-row w*16+l15

    if (tid < DCH) md_s[tid] = mask_d[(size_t)b * LD_ + d0 + tid];
    __syncthreads();   // drains STAGE(0) (vmcnt 0) + md_s visible

    // ---- group loop: staged-LDS D fragments + MFMA ----
    // B-frag lane (l15,quad): group row l15 (LDS stride 300 words = 12 mod 32
    // -> 2-way banks, free), cols t*32+quad*8..+8.
    floatx4 acc[NG];
    float dinvv[NG];
    floatx4 zero4 = {0.f, 0.f, 0.f, 0.f};
#pragma unroll
    for (int g = 0; g < NG; ++g) acc[g] = zero4;

#pragma unroll
    for (int g = 0; g < NG; ++g) {
        if (g + 1 < NG) STAGE(g + 1);            // prefetch next group
        // wait for group g's stage (counted: keep g+1's 5 loads in flight)
        if (g == 1 || g == 2) asm volatile("s_waitcnt vmcnt(5)" ::: "memory");
        if (g == 3)           asm volatile("s_waitcnt vmcnt(0)" ::: "memory");
        if (g) {                                  // g=0 covered by __syncthreads
            __builtin_amdgcn_s_barrier();         // all waves' stage(g) landed
            asm volatile("" ::: "memory");
        }

        const float* rowp = &sh.dbuf[(g & 1) * GF + l15 * E_];
        float lssd = 0.f;
#pragma unroll
        for (int t = 0; t < NT; ++t) {
            const int c0 = t * 32 + quad * 8;
            float4 a, c;
            if (t < NT - 1) {
                a = *(const float4*)(rowp + c0);
                c = *(const float4*)(rowp + c0 + 4);
            } else {   // tile 9 masking (rows are 300 floats in LDS)
                a = *(const float4*)(rowp + (quad <= 1 ? c0 : 0));
                c = *(const float4*)(rowp + (quad == 0 ? c0 + 4 : 0));
                a.x *= tm0; a.y *= tm0; a.z *= tm0; a.w *= tm0;
                c.x *= tm1; c.y *= tm1; c.z *= tm1; c.w *= tm1;
            }
            lssd += a.x * a.x + a.y * a.y + a.z * a.z + a.w * a.w;
            lssd += c.x * c.x + c.y * c.y + c.z * c.z + c.w * c.w;

            union { uint4 u; bf16x8 v; } bc;
            bc.u = make_uint4(pk2(a.x, a.y), pk2(a.z, a.w),
                              pk2(c.x, c.y), pk2(c.z, c.w));
            acc[g] = __builtin_amdgcn_mfma_f32_16x16x32_bf16(qf[t], bc.v, acc[g], 0, 0, 0);
        }
        // d inv-norm for group rows: 4 quads covered disjoint col ranges
        lssd += __shfl_xor(lssd, 16);
        lssd += __shfl_xor(lssd, 32);
        dinvv[g] = 1.0f / fmaxf(sqrtf(lssd), 1e-12f);

        if (g < 2) {   // before STAGE(g+2) may overwrite dbuf[g&1]
            asm volatile("" ::: "memory");
            __builtin_amdgcn_s_barrier();
            asm volatile("" ::: "memory");
        }
    }

    // ---- epilogue: normalized sims -> LDS (aliases dbuf), repartition, pool ----
    // Lane holds acc[g][r] = sim(q = w*16+quad*4+r, d = g*16+l15) (unnormalized).
    __syncthreads();   // all dbuf fragment reads done before aliasing as cs
    float qr[4];
#pragma unroll
    for (int r = 0; r < 4; ++r) qr[r] = __shfl(qinv, quad * 4 + r);
#pragma unroll
    for (int g = 0; g < NG; ++g) {
#pragma unroll
        for (int r = 0; r < 4; ++r) {
            const int q = w * 16 + quad * 4 + r;
            sh.cs[q * CSTR + g * 16 + l15] = acc[g][r] * qr[r] * dinvv[g];
        }
    }
    __syncthreads();

    // q-row x 16-d slice per thread: only 11 kacc registers live (round-3's
    // 44-wide kacc was the spill source)
    const int pq = tid >> 2, pd = tid & 3;
    union { float4 v[4]; float f[16]; } sb, mb;
#pragma unroll
    for (int i = 0; i < 4; ++i) {
        sb.v[i] = *(const float4*)&sh.cs[pq * CSTR + pd * 16 + i * 4];
        mb.v[i] = *(const float4*)&md_s[pd * 16 + i * 4];
    }

    float kacc[K_];
#pragma unroll
    for (int k = 0; k < K_; ++k) kacc[k] = 0.f;
#pragma unroll
    for (int j = 0; j < 16; ++j) {
        float s = sb.f[j];
        float m = mb.f[j];
        // kernel 0 (sigma=0.001): exact
        float df0 = s - 1.0f;
        kacc[0] = fmaf(__expf(df0 * df0 * -500000.0f), m, kacc[0]);
        // kernels 1..10: factorized (3 exps total)
        float t1 = __expf(fmaf(-50.0f * s, s, 90.0f * s));  // arg <= 40.5, no ovf
        float r  = __expf(-20.0f * s);
        float t  = t1 * m;
#pragma unroll
        for (int k = 1; k < K_; ++k) {
            kacc[k] = fmaf(t, CK2_C[k - 1], kacc[k]);
            t *= r;
        }
    }
#pragma unroll
    for (int msk = 1; msk <= 2; msk <<= 1)
#pragma unroll
        for (int k = 0; k < K_; ++k) kacc[k] += __shfl_xor(kacc[k], msk);

    if (pd == 0) {
        // layout [b][q][ch][k] -> final kernel reads 88 contiguous floats per q
        const size_t base = (((size_t)b * LQ_ + pq) * NCH + ch) * K_;
#pragma unroll
        for (int k = 0; k < K_; ++k) psum[base + k] = kacc[k];
    }
#undef STAGE
}

// Combine chunk partials, log-pool, dense + tanh. One wave per batch.
__global__ __launch_bounds__(64) void knrm_final(
    const float* __restrict__ psum, const float* __restrict__ mask_q,
    const float* __restrict__ dw, const float* __restrict__ db,
    float* __restrict__ out)
{
    const int b = blockIdx.x;
    const int q = threadIdx.x;  // 0..63

    const float* pp = psum + ((size_t)b * LQ_ + q) * (NCH * K_);
    union { float4 v[NCH * K_ / 4]; float f[NCH * K_]; } buf;  // 88 floats
#pragma unroll
    for (int i = 0; i < NCH * K_ / 4; ++i)
        buf.v[i] = *(const float4*)(pp + i * 4);

    float t = 0.0f;
#pragma unroll
    for (int k = 0; k < K_; ++k) {
        float p = 0.0f;
#pragma unroll
        for (int c = 0; c < NCH; ++c) p += buf.f[c * K_ + k];
        p = fmaxf(p, 1e-10f);
        t += logf(p) * dw[k];
    }
    t *= 0.01f * mask_q[(size_t)b * LQ_ + q];

#pragma unroll
    for (int m = 32; m >= 1; m >>= 1) t += __shfl_xor(t, m);
    if (q == 0) out[b] = tanhf(t + db[0]);
}

extern "C" void kernel_launch(void* const* d_in, const int* in_sizes, int n_in,
                              void* d_out, int out_size, void* d_ws, size_t ws_size,
                              hipStream_t stream) {
    const float* Q   = (const float*)d_in[0];  // [B, LQ, E]
    const float* D   = (const float*)d_in[1];  // [B, LD, E]
    const float* mq  = (const float*)d_in[2];  // [B, LQ]
    const float* md  = (const float*)d_in[3];  // [B, LD]
    const float* dw  = (const float*)d_in[4];  // [1, K]
    const float* db  = (const float*)d_in[5];  // [1]
    float* out  = (float*)d_out;               // [B, 1]
    float* psum = (float*)d_ws;                // [B][LQ][8][K] = 2.9 MB

    dim3 grid(B_, NCH);   // linear id = b + 128*ch -> XCD = b%8: same-batch
    knrm_main<<<grid, 256, 0, stream>>>(Q, D, md, psum);   // chunks share L2 Q
    knrm_final<<<B_, 64, 0, stream>>>(psum, mq, dw, db, out);
}